// Round 2
// baseline (299.557 us; speedup 1.0000x reference)
//
#include <hip/hip_runtime.h>
#include <math.h>

#define B_N 16384
#define F_N 128
#define H_N 128
#define E_N 32
#define ROWS (H_N + 1)   // 129 prefix rows per feature
// Interleaved table row (64 floats = 256 B):
//   row[eq*8 + 0..3] = A[e = eq*4 .. eq*4+3]
//   row[eq*8 + 4..7] = C[e = eq*4 .. eq*4+3]
// -> each apply thread reads its 32 bytes contiguously.

typedef float f4v __attribute__((ext_vector_type(4)));

__device__ __forceinline__ int eidxA(int e) { return ((e >> 2) << 3) | (e & 3); }

// ---------------------------------------------------------------------------
// Kernel A: per-feature table build. relu(x*w1+b1) is linear in x with one
// breakpoint t = -b1/w1. Sort thresholds; prefix tables over the active set.
// v4: same group-parallel scan as v3; table rows now e-quad interleaved.
// ---------------------------------------------------------------------------
__global__ __launch_bounds__(128) void build_tables(
    const float* __restrict__ w1, const float* __restrict__ b1,
    const float* __restrict__ w2, const float* __restrict__ b2,
    float* __restrict__ ts_out, float* __restrict__ tab)
{
    __shared__ float w1s[H_N], b1s[H_N], ts[H_N];
    __shared__ int   hidx[H_N];
    __shared__ float w2s[H_N * E_N];   // 16 KB
    __shared__ float dA[H_N * E_N];    // 16 KB
    __shared__ float dC[H_N * E_N];    // 16 KB
    __shared__ float baseA[4 * E_N], baseC[4 * E_N];
    __shared__ float gtA[4 * E_N], gtC[4 * E_N];

    const int f   = blockIdx.x;
    const int tid = threadIdx.x;

    float w1v = w1[f * H_N + tid];
    float b1v = b1[f * H_N + tid];
    w1s[tid] = w1v;
    b1s[tid] = b1v;
    ts[tid]   = (w1v != 0.0f) ? (-b1v / w1v) : INFINITY;
    hidx[tid] = tid;

    // stage w2[f]: 4096 floats = 1024 float4, 8 per thread, coalesced
    {
        const float4* src = (const float4*)(w2 + (size_t)f * H_N * E_N);
        float4*       dst = (float4*)w2s;
        #pragma unroll
        for (int it = 0; it < 8; ++it) dst[it * 128 + tid] = src[it * 128 + tid];
    }
    __syncthreads();

    // bitonic sort ascending by ts, payload hidx
    for (int k = 2; k <= H_N; k <<= 1) {
        for (int j = k >> 1; j > 0; j >>= 1) {
            int ixj = tid ^ j;
            if (ixj > tid) {
                float a = ts[tid], bv = ts[ixj];
                bool up = ((tid & k) == 0);
                bool sw = up ? (a > bv) : (a < bv);
                if (sw) {
                    int ia = hidx[tid];
                    ts[tid] = bv; ts[ixj] = a;
                    hidx[tid] = hidx[ixj]; hidx[ixj] = ia;
                }
            }
            __syncthreads();
        }
    }

    ts_out[f * H_N + tid] = ts[tid];

    const int e = tid & 31;    // embedding lane
    const int g = tid >> 5;    // 0..3 group

    // crossing deltas, all threads: group g handles sorted positions g*32..+31
    // (each thread only re-reads dA/dC elements it wrote itself -> no barrier
    //  needed between this and the scan below)
    #pragma unroll 4
    for (int jj = 0; jj < 32; ++jj) {
        int   j   = g * 32 + jj;
        int   p   = hidx[j];
        float w1h = w1s[p], b1h = b1s[p];
        float w2v = w2s[p * E_N + e];
        float s   = (w1h > 0.f) ? 1.f : ((w1h < 0.f) ? -1.f : 0.f);
        dA[j * E_N + e] = s * w1h * w2v;
        dC[j * E_N + e] = s * b1h * w2v;
    }
    // base state at x=-inf: group-partial sums
    {
        float pA = 0.f, pC = 0.f;
        #pragma unroll 4
        for (int hh = 0; hh < 32; ++hh) {
            int   h   = g * 32 + hh;
            float w1h = w1s[h], b1h = b1s[h];
            float w2v = w2s[h * E_N + e];
            if (w1h < 0.f) {
                pA = fmaf(w1h, w2v, pA);
                pC = fmaf(b1h, w2v, pC);
            } else if (w1h == 0.f && b1h > 0.f) {
                pC = fmaf(b1h, w2v, pC);
            }
        }
        baseA[g * E_N + e] = pA;
        baseC[g * E_N + e] = pC;
    }

    // group-local inclusive scan, in place
    {
        float aA = 0.f, aC = 0.f;
        for (int jj = 0; jj < 32; ++jj) {
            int idx = (g * 32 + jj) * E_N + e;
            aA += dA[idx]; dA[idx] = aA;
            aC += dC[idx]; dC[idx] = aC;
        }
        gtA[g * E_N + e] = aA;
        gtC[g * E_N + e] = aC;
    }
    __syncthreads();

    // offset for group g = full base + totals of groups < g
    float offA = baseA[e] + baseA[E_N + e] + baseA[2 * E_N + e] + baseA[3 * E_N + e];
    float offC = baseC[e] + baseC[E_N + e] + baseC[2 * E_N + e] + baseC[3 * E_N + e]
               + b2[f * E_N + e];
    for (int gg = 0; gg < g; ++gg) {
        offA += gtA[gg * E_N + e];
        offC += gtC[gg * E_N + e];
    }

    const size_t base = (size_t)f * ROWS * 64;
    const int    eA   = eidxA(e);
    if (g == 0) {                       // row 0 = base state
        tab[base + eA]     = offA;
        tab[base + eA + 4] = offC;
    }
    // rows g*32+1 .. g*32+32, written by all 128 threads
    #pragma unroll 4
    for (int jj = 0; jj < 32; ++jj) {
        int j = g * 32 + jj;
        tab[base + (size_t)(j + 1) * 64 + eA]     = offA + dA[j * E_N + e];
        tab[base + (size_t)(j + 1) * 64 + eA + 4] = offC + dC[j * E_N + e];
    }
}

// ---------------------------------------------------------------------------
// Kernel B: out[b,f,e] = x*A[f,r,e] + C[f,r,e], r = lower_bound(ts_f, x).
// v4: wave-local search->consume handoff via __shfl (no xs/los LDS, no
//     phase barriers), NB=32 / grid=2048 / launch_bounds(256,8):
//     LDS 16.5 KB -> 8 blocks/CU = 32 waves/CU (2x latency hiding).
//     Table rows e-quad interleaved -> 32 B contiguous per thread gather.
// ---------------------------------------------------------------------------
#define FH 32   // features per block
#define NB 32   // batch rows per block

__global__ __launch_bounds__(256, 8) void apply_tables(
    const float* __restrict__ x, const float* __restrict__ ts,
    const float* __restrict__ tab, float* __restrict__ out)
{
    __shared__ float lds_t[FH * ROWS];   // 16.5 KB (stride 129 -> conflict-free)

    const int tid = threadIdx.x;

    // bijective XCD remap: 2048 blocks round-robin over 8 XCDs ->
    // XCD k gets contiguous works [256k, 256k+256): 2 XCDs per feature
    // group, 1 MB table slice per XCD L2.
    const unsigned bid  = blockIdx.x;
    const unsigned work = (bid & 7u) * 256u + (bid >> 3);
    const int b0 = (int)(work & 511u) * NB;   // batch tile
    const int f0 = (int)(work >> 9)  * FH;    // feature group

    // stage sorted thresholds: FH*128 = 4096 floats = 1024 float4
    {
        const float4* src = (const float4*)(ts + (size_t)f0 * H_N);
        #pragma unroll
        for (int it = 0; it < 4; ++it) {
            int    vi  = it * 256 + tid;
            float4 v   = src[vi];
            int    idx = vi * 4;
            int    fl_ = idx >> 7;       // /128
            int    j   = idx & 127;
            float* dst = &lds_t[fl_ * ROWS + j];
            dst[0] = v.x; dst[1] = v.y; dst[2] = v.z; dst[3] = v.w;
        }
    }
    __syncthreads();

    const int lane = tid & 63;
    const int fl   = tid >> 3;        // 0..31 feature lane (8 per wave)
    const int eq   = tid & 7;         // dual role: search chunk id / e-quad

    // --- search phase: this lane searches rows r = eq*4 .. eq*4+3 of its
    // feature. 4 independent searches, step-major for LDS ILP.
    float xv[4]; int lo4[4];
    {
        const float* tloc = &lds_t[fl * ROWS];
        int hi4[4];
        #pragma unroll
        for (int j = 0; j < 4; ++j) {
            xv[j]  = x[(size_t)(b0 + eq * 4 + j) * F_N + f0 + fl];
            lo4[j] = 0; hi4[j] = H_N;
        }
        #pragma unroll
        for (int s = 0; s < 7; ++s) {
            #pragma unroll
            for (int j = 0; j < 4; ++j) {
                int  mid = (lo4[j] + hi4[j]) >> 1;
                bool lt  = tloc[mid] < xv[j];
                lo4[j] = lt ? mid + 1 : lo4[j];
                hi4[j] = lt ? hi4[j] : mid;
            }
        }
    }
    // no barrier: handoff is wave-local via shuffles below.

    // --- consume phase: thread (fl,eq) produces out[b0+r][f0+fl][eq*4..+3]
    // for all r; lo/xv fetched from the searcher lane (same fl-group,
    // lane (fl*8 | r>>2), register r&3).
    const float* tb = tab + (size_t)(f0 + fl) * ROWS * 64 + eq * 8;
    float*       op = out + (size_t)b0 * (F_N * E_N) + (size_t)(f0 + fl) * E_N + eq * 4;
    const int gbase = lane & 56;      // this fl-group's base lane

    for (int c = 0; c < 8; ++c) {
        #pragma unroll
        for (int j = 0; j < 4; ++j) {
            int   r   = c * 4 + j;
            int   lo  = __shfl(lo4[j], gbase | c);
            float xvr = __shfl(xv[j],  gbase | c);
            const float* row = tb + (size_t)lo * 64;
            f4v a  = *(const f4v*)(row);
            f4v cc = *(const f4v*)(row + 4);
            f4v o;
            o.x = fmaf(xvr, a.x, cc.x);
            o.y = fmaf(xvr, a.y, cc.y);
            o.z = fmaf(xvr, a.z, cc.z);
            o.w = fmaf(xvr, a.w, cc.w);
            __builtin_nontemporal_store(o, (f4v*)(op + (size_t)r * (F_N * E_N)));
        }
    }
}

// ---------------------------------------------------------------------------
// Fallback (only if d_ws is too small): direct fp32 compute.
// ---------------------------------------------------------------------------
__global__ __launch_bounds__(256) void direct_kernel(
    const float* __restrict__ x, const float* __restrict__ w1,
    const float* __restrict__ b1, const float* __restrict__ w2,
    const float* __restrict__ b2, float* __restrict__ out)
{
    __shared__ float w1s[H_N], b1s[H_N], b2s[E_N];
    __shared__ float w2s[H_N * E_N];
    const int f   = blockIdx.y;
    const int tid = threadIdx.x;
    if (tid < H_N) { w1s[tid] = w1[f * H_N + tid]; b1s[tid] = b1[f * H_N + tid]; }
    for (int i = tid; i < H_N * E_N; i += 256) w2s[i] = w2[(size_t)f * H_N * E_N + i];
    if (tid < E_N) b2s[tid] = b2[f * E_N + tid];
    __syncthreads();

    const int b  = blockIdx.x * 256 + tid;
    float xv = x[(size_t)b * F_N + f];
    float acc[E_N];
    #pragma unroll
    for (int e = 0; e < E_N; ++e) acc[e] = b2s[e];
    for (int h = 0; h < H_N; ++h) {
        float hv = fmaxf(fmaf(xv, w1s[h], b1s[h]), 0.f);
        #pragma unroll
        for (int e = 0; e < E_N; ++e) acc[e] = fmaf(hv, w2s[h * E_N + e], acc[e]);
    }
    float* op = out + (size_t)b * (F_N * E_N) + (size_t)f * E_N;
    #pragma unroll
    for (int e = 0; e < E_N; e += 4)
        *(float4*)(op + e) = make_float4(acc[e], acc[e + 1], acc[e + 2], acc[e + 3]);
}

extern "C" void kernel_launch(void* const* d_in, const int* in_sizes, int n_in,
                              void* d_out, int out_size, void* d_ws, size_t ws_size,
                              hipStream_t stream) {
    const float* x  = (const float*)d_in[0];
    const float* w1 = (const float*)d_in[1];
    const float* b1 = (const float*)d_in[2];
    const float* w2 = (const float*)d_in[3];
    const float* b2 = (const float*)d_in[4];
    float* out = (float*)d_out;

    const size_t n_ts  = (size_t)F_N * H_N;
    const size_t n_tab = (size_t)F_N * ROWS * 64;
    const size_t need  = (n_ts + n_tab) * sizeof(float);

    if (ws_size >= need) {
        float* ts  = (float*)d_ws;
        float* tab = ts + n_ts;
        build_tables<<<dim3(F_N), dim3(128), 0, stream>>>(w1, b1, w2, b2, ts, tab);
        apply_tables<<<dim3((B_N / NB) * (F_N / FH)), dim3(256), 0, stream>>>(x, ts, tab, out);
    } else {
        direct_kernel<<<dim3(B_N / 256, F_N), dim3(256), 0, stream>>>(x, w1, b1, w2, b2, out);
    }
}

// Round 3
// 294.351 us; speedup vs baseline: 1.0177x; 1.0177x over previous
//
#include <hip/hip_runtime.h>
#include <math.h>

#define B_N 16384
#define F_N 128
#define H_N 128
#define E_N 32
#define ROWS (H_N + 1)   // 129 prefix rows per feature
// Interleaved table row (64 floats = 256 B):
//   row[eq*8 + 0..3] = A[e = eq*4 .. eq*4+3]
//   row[eq*8 + 4..7] = C[e = eq*4 .. eq*4+3]
// -> each apply thread reads its 32 bytes contiguously.

typedef float f4v __attribute__((ext_vector_type(4)));

__device__ __forceinline__ int eidxA(int e) { return ((e >> 2) << 3) | (e & 3); }

// ---------------------------------------------------------------------------
// Kernel A: per-feature table build. relu(x*w1+b1) is linear in x with one
// breakpoint t = -b1/w1. Sort thresholds; prefix tables over the active set.
// (group-parallel scan; table rows e-quad interleaved). ~5 us, not the lever.
// ---------------------------------------------------------------------------
__global__ __launch_bounds__(128) void build_tables(
    const float* __restrict__ w1, const float* __restrict__ b1,
    const float* __restrict__ w2, const float* __restrict__ b2,
    float* __restrict__ ts_out, float* __restrict__ tab)
{
    __shared__ float w1s[H_N], b1s[H_N], ts[H_N];
    __shared__ int   hidx[H_N];
    __shared__ float w2s[H_N * E_N];   // 16 KB
    __shared__ float dA[H_N * E_N];    // 16 KB
    __shared__ float dC[H_N * E_N];    // 16 KB
    __shared__ float baseA[4 * E_N], baseC[4 * E_N];
    __shared__ float gtA[4 * E_N], gtC[4 * E_N];

    const int f   = blockIdx.x;
    const int tid = threadIdx.x;

    float w1v = w1[f * H_N + tid];
    float b1v = b1[f * H_N + tid];
    w1s[tid] = w1v;
    b1s[tid] = b1v;
    ts[tid]   = (w1v != 0.0f) ? (-b1v / w1v) : INFINITY;
    hidx[tid] = tid;

    // stage w2[f]: 4096 floats = 1024 float4, 8 per thread, coalesced
    {
        const float4* src = (const float4*)(w2 + (size_t)f * H_N * E_N);
        float4*       dst = (float4*)w2s;
        #pragma unroll
        for (int it = 0; it < 8; ++it) dst[it * 128 + tid] = src[it * 128 + tid];
    }
    __syncthreads();

    // bitonic sort ascending by ts, payload hidx
    for (int k = 2; k <= H_N; k <<= 1) {
        for (int j = k >> 1; j > 0; j >>= 1) {
            int ixj = tid ^ j;
            if (ixj > tid) {
                float a = ts[tid], bv = ts[ixj];
                bool up = ((tid & k) == 0);
                bool sw = up ? (a > bv) : (a < bv);
                if (sw) {
                    int ia = hidx[tid];
                    ts[tid] = bv; ts[ixj] = a;
                    hidx[tid] = hidx[ixj]; hidx[ixj] = ia;
                }
            }
            __syncthreads();
        }
    }

    ts_out[f * H_N + tid] = ts[tid];

    const int e = tid & 31;    // embedding lane
    const int g = tid >> 5;    // 0..3 group

    // crossing deltas: group g handles sorted positions g*32..+31
    #pragma unroll 4
    for (int jj = 0; jj < 32; ++jj) {
        int   j   = g * 32 + jj;
        int   p   = hidx[j];
        float w1h = w1s[p], b1h = b1s[p];
        float w2v = w2s[p * E_N + e];
        float s   = (w1h > 0.f) ? 1.f : ((w1h < 0.f) ? -1.f : 0.f);
        dA[j * E_N + e] = s * w1h * w2v;
        dC[j * E_N + e] = s * b1h * w2v;
    }
    // base state at x=-inf: group-partial sums
    {
        float pA = 0.f, pC = 0.f;
        #pragma unroll 4
        for (int hh = 0; hh < 32; ++hh) {
            int   h   = g * 32 + hh;
            float w1h = w1s[h], b1h = b1s[h];
            float w2v = w2s[h * E_N + e];
            if (w1h < 0.f) {
                pA = fmaf(w1h, w2v, pA);
                pC = fmaf(b1h, w2v, pC);
            } else if (w1h == 0.f && b1h > 0.f) {
                pC = fmaf(b1h, w2v, pC);
            }
        }
        baseA[g * E_N + e] = pA;
        baseC[g * E_N + e] = pC;
    }

    // group-local inclusive scan, in place
    {
        float aA = 0.f, aC = 0.f;
        for (int jj = 0; jj < 32; ++jj) {
            int idx = (g * 32 + jj) * E_N + e;
            aA += dA[idx]; dA[idx] = aA;
            aC += dC[idx]; dC[idx] = aC;
        }
        gtA[g * E_N + e] = aA;
        gtC[g * E_N + e] = aC;
    }
    __syncthreads();

    // offset for group g = full base + totals of groups < g
    float offA = baseA[e] + baseA[E_N + e] + baseA[2 * E_N + e] + baseA[3 * E_N + e];
    float offC = baseC[e] + baseC[E_N + e] + baseC[2 * E_N + e] + baseC[3 * E_N + e]
               + b2[f * E_N + e];
    for (int gg = 0; gg < g; ++gg) {
        offA += gtA[gg * E_N + e];
        offC += gtC[gg * E_N + e];
    }

    const size_t base = (size_t)f * ROWS * 64;
    const int    eA   = eidxA(e);
    if (g == 0) {                       // row 0 = base state
        tab[base + eA]     = offA;
        tab[base + eA + 4] = offC;
    }
    // rows g*32+1 .. g*32+32, written by all 128 threads
    #pragma unroll 4
    for (int jj = 0; jj < 32; ++jj) {
        int j = g * 32 + jj;
        tab[base + (size_t)(j + 1) * 64 + eA]     = offA + dA[j * E_N + e];
        tab[base + (size_t)(j + 1) * 64 + eA + 4] = offC + dC[j * E_N + e];
    }
}

// ---------------------------------------------------------------------------
// Kernel B: out[b,f,e] = x*A[f,r,e] + C[f,r,e], r = lower_bound(ts_f, x).
// v5: v3 structure (coalesced staging, search-dedup via LDS, batched
//     gather/FMA/NT-store) with occupancy fixed:
//     FH 32->16: LDS 32.5 -> 14.3 KB (los stored as ushort) -> 6 blocks/CU
//     via __launch_bounds__(256,6) = 24 waves/CU (1.5x v3).
//     8 feature groups => exact XCD<->group pinning: f0 = (bid&7)*16, each
//     XCD's L2 holds one 528 KB table slice.
// ---------------------------------------------------------------------------
#define FH 16   // features per block
#define NB 64   // batch rows per block

__global__ __launch_bounds__(256, 6) void apply_tables(
    const float* __restrict__ x, const float* __restrict__ ts,
    const float* __restrict__ tab, float* __restrict__ out)
{
    __shared__ float          lds_t[FH * ROWS];  // 8.25 KB (stride 129)
    __shared__ float          xs[NB * FH];       // 4 KB
    __shared__ unsigned short los[NB * FH];      // 2 KB

    const int tid = threadIdx.x;

    // XCD pinning: round-robin dispatch sends bid%8 to XCD (bid%8);
    // give that XCD always the same feature group.
    const unsigned bid = blockIdx.x;             // 2048 blocks
    const int f0 = (int)(bid & 7u) * FH;         // feature group 0..7
    const int b0 = (int)(bid >> 3) * NB;         // batch tile 0..255

    // stage sorted thresholds: FH*128 = 2048 floats = 512 float4, 2/thread
    {
        const float4* src = (const float4*)(ts + (size_t)f0 * H_N);
        #pragma unroll
        for (int it = 0; it < 2; ++it) {
            int    vi  = it * 256 + tid;
            float4 v   = src[vi];
            int    idx = vi * 4;
            int    fl_ = idx >> 7;       // /128
            int    j   = idx & 127;
            float* dst = &lds_t[fl_ * ROWS + j];
            dst[0] = v.x; dst[1] = v.y; dst[2] = v.z; dst[3] = v.w;
        }
    }
    // stage x tile: NB x FH = 1024 floats = 256 float4, 1/thread
    {
        int bl = tid >> 2;               // 4 float4 per row of 16
        int fq = (tid & 3) * 4;
        float4 v = *(const float4*)(x + (size_t)(b0 + bl) * F_N + f0 + fq);
        *(float4*)(&xs[bl * FH + fq]) = v;
    }
    __syncthreads();

    // Phase A: binary search once per (row, feature): 1024 searches/block,
    // 4 per thread, step-major for 4-wide LDS ILP.
    {
        const int fa = tid & 15;         // feature lane
        const int rg = tid >> 4;         // 0..15, rows rg*4..rg*4+3
        const float* tloc = &lds_t[fa * ROWS];
        float xv[4];
        int   lo[4], hi[4];
        #pragma unroll
        for (int j = 0; j < 4; ++j) {
            xv[j] = xs[(rg * 4 + j) * FH + fa];
            lo[j] = 0; hi[j] = H_N;
        }
        #pragma unroll
        for (int s = 0; s < 7; ++s) {
            #pragma unroll
            for (int j = 0; j < 4; ++j) {
                int  mid = (lo[j] + hi[j]) >> 1;
                bool lt  = tloc[mid] < xv[j];
                lo[j] = lt ? mid + 1 : lo[j];
                hi[j] = lt ? hi[j] : mid;
            }
        }
        #pragma unroll
        for (int j = 0; j < 4; ++j)
            los[(rg * 4 + j) * FH + fa] = (unsigned short)lo[j];
    }
    __syncthreads();

    // Phase B: gather + FMA + non-temporal coalesced stores.
    // thread (bh, fl, eq) covers rows bh*32..bh*32+31 of feature f0+fl,
    // embedding quad eq. Waves store 8 features x 128 B = 1 KB contiguous.
    const int fl = (tid >> 3) & 15;      // feature lane
    const int eq = tid & 7;              // e-quad
    const int bh = tid >> 7;             // batch half (0..1)
    const int rbase = bh * 32;
    const float* tb = tab + (size_t)(f0 + fl) * ROWS * 64 + eq * 8;
    float*       op = out + (size_t)(b0 + rbase) * (F_N * E_N)
                          + (size_t)(f0 + fl) * E_N + eq * 4;

    #pragma unroll 4
    for (int r = 0; r < 32; ++r) {
        int   lo = los[(rbase + r) * FH + fl];   // broadcast within e-quad
        float xv = xs[(rbase + r) * FH + fl];
        const float* row = tb + (size_t)lo * 64;
        f4v a  = *(const f4v*)(row);
        f4v cc = *(const f4v*)(row + 4);
        f4v o;
        o.x = fmaf(xv, a.x, cc.x);
        o.y = fmaf(xv, a.y, cc.y);
        o.z = fmaf(xv, a.z, cc.z);
        o.w = fmaf(xv, a.w, cc.w);
        __builtin_nontemporal_store(o, (f4v*)(op + (size_t)r * (F_N * E_N)));
    }
}

// ---------------------------------------------------------------------------
// Fallback (only if d_ws is too small): direct fp32 compute.
// ---------------------------------------------------------------------------
__global__ __launch_bounds__(256) void direct_kernel(
    const float* __restrict__ x, const float* __restrict__ w1,
    const float* __restrict__ b1, const float* __restrict__ w2,
    const float* __restrict__ b2, float* __restrict__ out)
{
    __shared__ float w1s[H_N], b1s[H_N], b2s[E_N];
    __shared__ float w2s[H_N * E_N];
    const int f   = blockIdx.y;
    const int tid = threadIdx.x;
    if (tid < H_N) { w1s[tid] = w1[f * H_N + tid]; b1s[tid] = b1[f * H_N + tid]; }
    for (int i = tid; i < H_N * E_N; i += 256) w2s[i] = w2[(size_t)f * H_N * E_N + i];
    if (tid < E_N) b2s[tid] = b2[f * E_N + tid];
    __syncthreads();

    const int b  = blockIdx.x * 256 + tid;
    float xv = x[(size_t)b * F_N + f];
    float acc[E_N];
    #pragma unroll
    for (int e = 0; e < E_N; ++e) acc[e] = b2s[e];
    for (int h = 0; h < H_N; ++h) {
        float hv = fmaxf(fmaf(xv, w1s[h], b1s[h]), 0.f);
        #pragma unroll
        for (int e = 0; e < E_N; ++e) acc[e] = fmaf(hv, w2s[h * E_N + e], acc[e]);
    }
    float* op = out + (size_t)b * (F_N * E_N) + (size_t)f * E_N;
    #pragma unroll
    for (int e = 0; e < E_N; e += 4)
        *(float4*)(op + e) = make_float4(acc[e], acc[e + 1], acc[e + 2], acc[e + 3]);
}

extern "C" void kernel_launch(void* const* d_in, const int* in_sizes, int n_in,
                              void* d_out, int out_size, void* d_ws, size_t ws_size,
                              hipStream_t stream) {
    const float* x  = (const float*)d_in[0];
    const float* w1 = (const float*)d_in[1];
    const float* b1 = (const float*)d_in[2];
    const float* w2 = (const float*)d_in[3];
    const float* b2 = (const float*)d_in[4];
    float* out = (float*)d_out;

    const size_t n_ts  = (size_t)F_N * H_N;
    const size_t n_tab = (size_t)F_N * ROWS * 64;
    const size_t need  = (n_ts + n_tab) * sizeof(float);

    if (ws_size >= need) {
        float* ts  = (float*)d_ws;
        float* tab = ts + n_ts;
        build_tables<<<dim3(F_N), dim3(128), 0, stream>>>(w1, b1, w2, b2, ts, tab);
        apply_tables<<<dim3((B_N / NB) * (F_N / FH)), dim3(256), 0, stream>>>(x, ts, tab, out);
    } else {
        direct_kernel<<<dim3(B_N / 256, F_N), dim3(256), 0, stream>>>(x, w1, b1, w2, b2, out);
    }
}

// Round 4
// 294.137 us; speedup vs baseline: 1.0184x; 1.0007x over previous
//
#include <hip/hip_runtime.h>
#include <math.h>

#define B_N 16384
#define F_N 128
#define H_N 128
#define E_N 32
#define ROWS (H_N + 1)   // 129 prefix rows per feature
// Interleaved table row (64 floats = 256 B):
//   row[eq*8 + 0..3] = A[e = eq*4 .. eq*4+3]
//   row[eq*8 + 4..7] = C[e = eq*4 .. eq*4+3]
// -> each apply thread reads its 32 bytes contiguously.

typedef float f4v __attribute__((ext_vector_type(4)));

__device__ __forceinline__ int eidxA(int e) { return ((e >> 2) << 3) | (e & 3); }

// ---------------------------------------------------------------------------
// Kernel A: per-feature table build. relu(x*w1+b1) is linear in x with one
// breakpoint t = -b1/w1. Sort thresholds; prefix tables over the active set.
// (group-parallel scan; table rows e-quad interleaved). ~5-10 us.
// ---------------------------------------------------------------------------
__global__ __launch_bounds__(128) void build_tables(
    const float* __restrict__ w1, const float* __restrict__ b1,
    const float* __restrict__ w2, const float* __restrict__ b2,
    float* __restrict__ ts_out, float* __restrict__ tab)
{
    __shared__ float w1s[H_N], b1s[H_N], ts[H_N];
    __shared__ int   hidx[H_N];
    __shared__ float w2s[H_N * E_N];   // 16 KB
    __shared__ float dA[H_N * E_N];    // 16 KB
    __shared__ float dC[H_N * E_N];    // 16 KB
    __shared__ float baseA[4 * E_N], baseC[4 * E_N];
    __shared__ float gtA[4 * E_N], gtC[4 * E_N];

    const int f   = blockIdx.x;
    const int tid = threadIdx.x;

    float w1v = w1[f * H_N + tid];
    float b1v = b1[f * H_N + tid];
    w1s[tid] = w1v;
    b1s[tid] = b1v;
    ts[tid]   = (w1v != 0.0f) ? (-b1v / w1v) : INFINITY;
    hidx[tid] = tid;

    // stage w2[f]: 4096 floats = 1024 float4, 8 per thread, coalesced
    {
        const float4* src = (const float4*)(w2 + (size_t)f * H_N * E_N);
        float4*       dst = (float4*)w2s;
        #pragma unroll
        for (int it = 0; it < 8; ++it) dst[it * 128 + tid] = src[it * 128 + tid];
    }
    __syncthreads();

    // bitonic sort ascending by ts, payload hidx
    for (int k = 2; k <= H_N; k <<= 1) {
        for (int j = k >> 1; j > 0; j >>= 1) {
            int ixj = tid ^ j;
            if (ixj > tid) {
                float a = ts[tid], bv = ts[ixj];
                bool up = ((tid & k) == 0);
                bool sw = up ? (a > bv) : (a < bv);
                if (sw) {
                    int ia = hidx[tid];
                    ts[tid] = bv; ts[ixj] = a;
                    hidx[tid] = hidx[ixj]; hidx[ixj] = ia;
                }
            }
            __syncthreads();
        }
    }

    ts_out[f * H_N + tid] = ts[tid];

    const int e = tid & 31;    // embedding lane
    const int g = tid >> 5;    // 0..3 group

    // crossing deltas: group g handles sorted positions g*32..+31
    #pragma unroll 4
    for (int jj = 0; jj < 32; ++jj) {
        int   j   = g * 32 + jj;
        int   p   = hidx[j];
        float w1h = w1s[p], b1h = b1s[p];
        float w2v = w2s[p * E_N + e];
        float s   = (w1h > 0.f) ? 1.f : ((w1h < 0.f) ? -1.f : 0.f);
        dA[j * E_N + e] = s * w1h * w2v;
        dC[j * E_N + e] = s * b1h * w2v;
    }
    // base state at x=-inf: group-partial sums
    {
        float pA = 0.f, pC = 0.f;
        #pragma unroll 4
        for (int hh = 0; hh < 32; ++hh) {
            int   h   = g * 32 + hh;
            float w1h = w1s[h], b1h = b1s[h];
            float w2v = w2s[h * E_N + e];
            if (w1h < 0.f) {
                pA = fmaf(w1h, w2v, pA);
                pC = fmaf(b1h, w2v, pC);
            } else if (w1h == 0.f && b1h > 0.f) {
                pC = fmaf(b1h, w2v, pC);
            }
        }
        baseA[g * E_N + e] = pA;
        baseC[g * E_N + e] = pC;
    }

    // group-local inclusive scan, in place
    {
        float aA = 0.f, aC = 0.f;
        for (int jj = 0; jj < 32; ++jj) {
            int idx = (g * 32 + jj) * E_N + e;
            aA += dA[idx]; dA[idx] = aA;
            aC += dC[idx]; dC[idx] = aC;
        }
        gtA[g * E_N + e] = aA;
        gtC[g * E_N + e] = aC;
    }
    __syncthreads();

    // offset for group g = full base + totals of groups < g
    float offA = baseA[e] + baseA[E_N + e] + baseA[2 * E_N + e] + baseA[3 * E_N + e];
    float offC = baseC[e] + baseC[E_N + e] + baseC[2 * E_N + e] + baseC[3 * E_N + e]
               + b2[f * E_N + e];
    for (int gg = 0; gg < g; ++gg) {
        offA += gtA[gg * E_N + e];
        offC += gtC[gg * E_N + e];
    }

    const size_t base = (size_t)f * ROWS * 64;
    const int    eA   = eidxA(e);
    if (g == 0) {                       // row 0 = base state
        tab[base + eA]     = offA;
        tab[base + eA + 4] = offC;
    }
    // rows g*32+1 .. g*32+32, written by all 128 threads
    #pragma unroll 4
    for (int jj = 0; jj < 32; ++jj) {
        int j = g * 32 + jj;
        tab[base + (size_t)(j + 1) * 64 + eA]     = offA + dA[j * E_N + e];
        tab[base + (size_t)(j + 1) * 64 + eA + 4] = offC + dC[j * E_N + e];
    }
}

// ---------------------------------------------------------------------------
// Kernel B: out[b,f,e] = x*A[f,r,e] + C[f,r,e], r = lower_bound(ts_f, x).
// v6: fully-resident grid. LDS 14.3 KB, __launch_bounds__(256,8) ->
//     8 blocks/CU, all 2048 blocks co-resident in ONE dispatch wave:
//     zero scheduling tail + 32 waves/CU for gather-latency hiding.
//     Phase B at unroll 2 to stay within the 64-VGPR cap (no spill).
// ---------------------------------------------------------------------------
#define FH 16   // features per block
#define NB 64   // batch rows per block

__global__ __launch_bounds__(256, 8) void apply_tables(
    const float* __restrict__ x, const float* __restrict__ ts,
    const float* __restrict__ tab, float* __restrict__ out)
{
    __shared__ float          lds_t[FH * ROWS];  // 8.25 KB (stride 129)
    __shared__ float          xs[NB * FH];       // 4 KB
    __shared__ unsigned short los[NB * FH];      // 2 KB

    const int tid = threadIdx.x;

    // XCD pinning: round-robin dispatch sends bid%8 to XCD (bid%8);
    // give that XCD always the same feature group (528 KB table slice).
    const unsigned bid = blockIdx.x;             // 2048 blocks
    const int f0 = (int)(bid & 7u) * FH;         // feature group 0..7
    const int b0 = (int)(bid >> 3) * NB;         // batch tile 0..255

    // stage sorted thresholds: FH*128 = 2048 floats = 512 float4, 2/thread
    {
        const float4* src = (const float4*)(ts + (size_t)f0 * H_N);
        #pragma unroll
        for (int it = 0; it < 2; ++it) {
            int    vi  = it * 256 + tid;
            float4 v   = src[vi];
            int    idx = vi * 4;
            int    fl_ = idx >> 7;       // /128
            int    j   = idx & 127;
            float* dst = &lds_t[fl_ * ROWS + j];
            dst[0] = v.x; dst[1] = v.y; dst[2] = v.z; dst[3] = v.w;
        }
    }
    // stage x tile: NB x FH = 1024 floats = 256 float4, 1/thread
    {
        int bl = tid >> 2;               // 4 float4 per row of 16
        int fq = (tid & 3) * 4;
        float4 v = *(const float4*)(x + (size_t)(b0 + bl) * F_N + f0 + fq);
        *(float4*)(&xs[bl * FH + fq]) = v;
    }
    __syncthreads();

    // Phase A: binary search once per (row, feature): 1024 searches/block,
    // 4 per thread, step-major for 4-wide LDS ILP.
    {
        const int fa = tid & 15;         // feature lane
        const int rg = tid >> 4;         // 0..15, rows rg*4..rg*4+3
        const float* tloc = &lds_t[fa * ROWS];
        float xv[4];
        int   lo[4], hi[4];
        #pragma unroll
        for (int j = 0; j < 4; ++j) {
            xv[j] = xs[(rg * 4 + j) * FH + fa];
            lo[j] = 0; hi[j] = H_N;
        }
        #pragma unroll
        for (int s = 0; s < 7; ++s) {
            #pragma unroll
            for (int j = 0; j < 4; ++j) {
                int  mid = (lo[j] + hi[j]) >> 1;
                bool lt  = tloc[mid] < xv[j];
                lo[j] = lt ? mid + 1 : lo[j];
                hi[j] = lt ? hi[j] : mid;
            }
        }
        #pragma unroll
        for (int j = 0; j < 4; ++j)
            los[(rg * 4 + j) * FH + fa] = (unsigned short)lo[j];
    }
    __syncthreads();

    // Phase B: gather + FMA + non-temporal coalesced stores.
    // thread (bh, fl, eq) covers rows bh*32..bh*32+31 of feature f0+fl,
    // embedding quad eq. Waves store 8 features x 128 B = 1 KB contiguous.
    const int fl = (tid >> 3) & 15;      // feature lane
    const int eq = tid & 7;              // e-quad
    const int bh = tid >> 7;             // batch half (0..1)
    const int rbase = bh * 32;
    const f4v* tb = (const f4v*)(tab + (size_t)(f0 + fl) * ROWS * 64 + eq * 8);
    float*     op = out + (size_t)(b0 + rbase) * (F_N * E_N)
                        + (size_t)(f0 + fl) * E_N + eq * 4;

    #pragma unroll 2
    for (int r = 0; r < 32; ++r) {
        int   lo = los[(rbase + r) * FH + fl];   // broadcast within e-quad
        float xv = xs[(rbase + r) * FH + fl];
        f4v a  = tb[lo * 16];
        f4v cc = tb[lo * 16 + 1];
        f4v o;
        o.x = fmaf(xv, a.x, cc.x);
        o.y = fmaf(xv, a.y, cc.y);
        o.z = fmaf(xv, a.z, cc.z);
        o.w = fmaf(xv, a.w, cc.w);
        __builtin_nontemporal_store(o, (f4v*)(op + (size_t)r * (F_N * E_N)));
    }
}

// ---------------------------------------------------------------------------
// Fallback (only if d_ws is too small): direct fp32 compute.
// ---------------------------------------------------------------------------
__global__ __launch_bounds__(256) void direct_kernel(
    const float* __restrict__ x, const float* __restrict__ w1,
    const float* __restrict__ b1, const float* __restrict__ w2,
    const float* __restrict__ b2, float* __restrict__ out)
{
    __shared__ float w1s[H_N], b1s[H_N], b2s[E_N];
    __shared__ float w2s[H_N * E_N];
    const int f   = blockIdx.y;
    const int tid = threadIdx.x;
    if (tid < H_N) { w1s[tid] = w1[f * H_N + tid]; b1s[tid] = b1[f * H_N + tid]; }
    for (int i = tid; i < H_N * E_N; i += 256) w2s[i] = w2[(size_t)f * H_N * E_N + i];
    if (tid < E_N) b2s[tid] = b2[f * E_N + tid];
    __syncthreads();

    const int b  = blockIdx.x * 256 + tid;
    float xv = x[(size_t)b * F_N + f];
    float acc[E_N];
    #pragma unroll
    for (int e = 0; e < E_N; ++e) acc[e] = b2s[e];
    for (int h = 0; h < H_N; ++h) {
        float hv = fmaxf(fmaf(xv, w1s[h], b1s[h]), 0.f);
        #pragma unroll
        for (int e = 0; e < E_N; ++e) acc[e] = fmaf(hv, w2s[h * E_N + e], acc[e]);
    }
    float* op = out + (size_t)b * (F_N * E_N) + (size_t)f * E_N;
    #pragma unroll
    for (int e = 0; e < E_N; e += 4)
        *(float4*)(op + e) = make_float4(acc[e], acc[e + 1], acc[e + 2], acc[e + 3]);
}

extern "C" void kernel_launch(void* const* d_in, const int* in_sizes, int n_in,
                              void* d_out, int out_size, void* d_ws, size_t ws_size,
                              hipStream_t stream) {
    const float* x  = (const float*)d_in[0];
    const float* w1 = (const float*)d_in[1];
    const float* b1 = (const float*)d_in[2];
    const float* w2 = (const float*)d_in[3];
    const float* b2 = (const float*)d_in[4];
    float* out = (float*)d_out;

    const size_t n_ts  = (size_t)F_N * H_N;
    const size_t n_tab = (size_t)F_N * ROWS * 64;
    const size_t need  = (n_ts + n_tab) * sizeof(float);

    if (ws_size >= need) {
        float* ts  = (float*)d_ws;
        float* tab = ts + n_ts;
        build_tables<<<dim3(F_N), dim3(128), 0, stream>>>(w1, b1, w2, b2, ts, tab);
        apply_tables<<<dim3((B_N / NB) * (F_N / FH)), dim3(256), 0, stream>>>(x, ts, tab, out);
    } else {
        direct_kernel<<<dim3(B_N / 256, F_N), dim3(256), 0, stream>>>(x, w1, b1, w2, b2, out);
    }
}

// Round 5
// 293.795 us; speedup vs baseline: 1.0196x; 1.0012x over previous
//
#include <hip/hip_runtime.h>
#include <math.h>

#define B_N 16384
#define F_N 128
#define H_N 128
#define E_N 32
#define ROWS (H_N + 1)   // 129 prefix rows per feature
// Interleaved table row (64 floats = 256 B):
//   row[eq*8 + 0..3] = A[e = eq*4 .. eq*4+3]
//   row[eq*8 + 4..7] = C[e = eq*4 .. eq*4+3]
// -> each apply thread reads its 32 bytes contiguously.

typedef float f4v __attribute__((ext_vector_type(4)));

__device__ __forceinline__ int eidxA(int e) { return ((e >> 2) << 3) | (e & 3); }

// ---------------------------------------------------------------------------
// Kernel A: per-feature table build. relu(x*w1+b1) is linear in x with one
// breakpoint t = -b1/w1. Sort thresholds; prefix tables over the active set.
// (group-parallel scan; table rows e-quad interleaved). ~5-10 us.
// ---------------------------------------------------------------------------
__global__ __launch_bounds__(128) void build_tables(
    const float* __restrict__ w1, const float* __restrict__ b1,
    const float* __restrict__ w2, const float* __restrict__ b2,
    float* __restrict__ ts_out, float* __restrict__ tab)
{
    __shared__ float w1s[H_N], b1s[H_N], ts[H_N];
    __shared__ int   hidx[H_N];
    __shared__ float w2s[H_N * E_N];   // 16 KB
    __shared__ float dA[H_N * E_N];    // 16 KB
    __shared__ float dC[H_N * E_N];    // 16 KB
    __shared__ float baseA[4 * E_N], baseC[4 * E_N];
    __shared__ float gtA[4 * E_N], gtC[4 * E_N];

    const int f   = blockIdx.x;
    const int tid = threadIdx.x;

    float w1v = w1[f * H_N + tid];
    float b1v = b1[f * H_N + tid];
    w1s[tid] = w1v;
    b1s[tid] = b1v;
    ts[tid]   = (w1v != 0.0f) ? (-b1v / w1v) : INFINITY;
    hidx[tid] = tid;

    // stage w2[f]: 4096 floats = 1024 float4, 8 per thread, coalesced
    {
        const float4* src = (const float4*)(w2 + (size_t)f * H_N * E_N);
        float4*       dst = (float4*)w2s;
        #pragma unroll
        for (int it = 0; it < 8; ++it) dst[it * 128 + tid] = src[it * 128 + tid];
    }
    __syncthreads();

    // bitonic sort ascending by ts, payload hidx
    for (int k = 2; k <= H_N; k <<= 1) {
        for (int j = k >> 1; j > 0; j >>= 1) {
            int ixj = tid ^ j;
            if (ixj > tid) {
                float a = ts[tid], bv = ts[ixj];
                bool up = ((tid & k) == 0);
                bool sw = up ? (a > bv) : (a < bv);
                if (sw) {
                    int ia = hidx[tid];
                    ts[tid] = bv; ts[ixj] = a;
                    hidx[tid] = hidx[ixj]; hidx[ixj] = ia;
                }
            }
            __syncthreads();
        }
    }

    ts_out[f * H_N + tid] = ts[tid];

    const int e = tid & 31;    // embedding lane
    const int g = tid >> 5;    // 0..3 group

    // crossing deltas: group g handles sorted positions g*32..+31
    #pragma unroll 4
    for (int jj = 0; jj < 32; ++jj) {
        int   j   = g * 32 + jj;
        int   p   = hidx[j];
        float w1h = w1s[p], b1h = b1s[p];
        float w2v = w2s[p * E_N + e];
        float s   = (w1h > 0.f) ? 1.f : ((w1h < 0.f) ? -1.f : 0.f);
        dA[j * E_N + e] = s * w1h * w2v;
        dC[j * E_N + e] = s * b1h * w2v;
    }
    // base state at x=-inf: group-partial sums
    {
        float pA = 0.f, pC = 0.f;
        #pragma unroll 4
        for (int hh = 0; hh < 32; ++hh) {
            int   h   = g * 32 + hh;
            float w1h = w1s[h], b1h = b1s[h];
            float w2v = w2s[h * E_N + e];
            if (w1h < 0.f) {
                pA = fmaf(w1h, w2v, pA);
                pC = fmaf(b1h, w2v, pC);
            } else if (w1h == 0.f && b1h > 0.f) {
                pC = fmaf(b1h, w2v, pC);
            }
        }
        baseA[g * E_N + e] = pA;
        baseC[g * E_N + e] = pC;
    }

    // group-local inclusive scan, in place
    {
        float aA = 0.f, aC = 0.f;
        for (int jj = 0; jj < 32; ++jj) {
            int idx = (g * 32 + jj) * E_N + e;
            aA += dA[idx]; dA[idx] = aA;
            aC += dC[idx]; dC[idx] = aC;
        }
        gtA[g * E_N + e] = aA;
        gtC[g * E_N + e] = aC;
    }
    __syncthreads();

    // offset for group g = full base + totals of groups < g
    float offA = baseA[e] + baseA[E_N + e] + baseA[2 * E_N + e] + baseA[3 * E_N + e];
    float offC = baseC[e] + baseC[E_N + e] + baseC[2 * E_N + e] + baseC[3 * E_N + e]
               + b2[f * E_N + e];
    for (int gg = 0; gg < g; ++gg) {
        offA += gtA[gg * E_N + e];
        offC += gtC[gg * E_N + e];
    }

    const size_t base = (size_t)f * ROWS * 64;
    const int    eA   = eidxA(e);
    if (g == 0) {                       // row 0 = base state
        tab[base + eA]     = offA;
        tab[base + eA + 4] = offC;
    }
    // rows g*32+1 .. g*32+32, written by all 128 threads
    #pragma unroll 4
    for (int jj = 0; jj < 32; ++jj) {
        int j = g * 32 + jj;
        tab[base + (size_t)(j + 1) * 64 + eA]     = offA + dA[j * E_N + e];
        tab[base + (size_t)(j + 1) * 64 + eA + 4] = offC + dC[j * E_N + e];
    }
}

// ---------------------------------------------------------------------------
// Kernel B: out[b,f,e] = x*A[f,r,e] + C[f,r,e], r = lower_bound(ts_f, x).
// v7: Phase B restructured into load-cluster / store-cluster batches of 8.
//     CDNA has a SINGLE in-order vmcnt for loads AND stores: interleaving
//     gather->FMA->store per row makes every gather-wait also wait on the
//     previous iteration's HBM store ack (store-latency serialization).
//     Batching 16 independent gathers before 8 stores cuts that coupling 8x.
//     launch_bounds(256,4): 128-VGPR cap for the 64-reg gather batch
//     (R3/R4 showed occupancy 4..8 blk/CU is perf-neutral).
// ---------------------------------------------------------------------------
#define FH 16   // features per block
#define NB 64   // batch rows per block

__global__ __launch_bounds__(256, 4) void apply_tables(
    const float* __restrict__ x, const float* __restrict__ ts,
    const float* __restrict__ tab, float* __restrict__ out)
{
    __shared__ float          lds_t[FH * ROWS];  // 8.25 KB (stride 129)
    __shared__ float          xs[NB * FH];       // 4 KB
    __shared__ unsigned short los[NB * FH];      // 2 KB

    const int tid = threadIdx.x;

    // XCD pinning: round-robin dispatch sends bid%8 to XCD (bid%8);
    // give that XCD always the same feature group (528 KB table slice).
    const unsigned bid = blockIdx.x;             // 2048 blocks
    const int f0 = (int)(bid & 7u) * FH;         // feature group 0..7
    const int b0 = (int)(bid >> 3) * NB;         // batch tile 0..255

    // stage sorted thresholds: FH*128 = 2048 floats = 512 float4, 2/thread
    {
        const float4* src = (const float4*)(ts + (size_t)f0 * H_N);
        #pragma unroll
        for (int it = 0; it < 2; ++it) {
            int    vi  = it * 256 + tid;
            float4 v   = src[vi];
            int    idx = vi * 4;
            int    fl_ = idx >> 7;       // /128
            int    j   = idx & 127;
            float* dst = &lds_t[fl_ * ROWS + j];
            dst[0] = v.x; dst[1] = v.y; dst[2] = v.z; dst[3] = v.w;
        }
    }
    // stage x tile: NB x FH = 1024 floats = 256 float4, 1/thread
    {
        int bl = tid >> 2;               // 4 float4 per row of 16
        int fq = (tid & 3) * 4;
        float4 v = *(const float4*)(x + (size_t)(b0 + bl) * F_N + f0 + fq);
        *(float4*)(&xs[bl * FH + fq]) = v;
    }
    __syncthreads();

    // Phase A: binary search once per (row, feature): 1024 searches/block,
    // 4 per thread, step-major for 4-wide LDS ILP.
    {
        const int fa = tid & 15;         // feature lane
        const int rg = tid >> 4;         // 0..15, rows rg*4..rg*4+3
        const float* tloc = &lds_t[fa * ROWS];
        float xv[4];
        int   lo[4], hi[4];
        #pragma unroll
        for (int j = 0; j < 4; ++j) {
            xv[j] = xs[(rg * 4 + j) * FH + fa];
            lo[j] = 0; hi[j] = H_N;
        }
        #pragma unroll
        for (int s = 0; s < 7; ++s) {
            #pragma unroll
            for (int j = 0; j < 4; ++j) {
                int  mid = (lo[j] + hi[j]) >> 1;
                bool lt  = tloc[mid] < xv[j];
                lo[j] = lt ? mid + 1 : lo[j];
                hi[j] = lt ? hi[j] : mid;
            }
        }
        #pragma unroll
        for (int j = 0; j < 4; ++j)
            los[(rg * 4 + j) * FH + fa] = (unsigned short)lo[j];
    }
    __syncthreads();

    // Phase B: batched gather / FMA / NT-store.
    // thread (bh, fl, eq) covers rows bh*32..bh*32+31 of feature f0+fl,
    // embedding quad eq. Waves store 8 features x 128 B = 1 KB contiguous.
    const int fl = (tid >> 3) & 15;      // feature lane
    const int eq = tid & 7;              // e-quad
    const int bh = tid >> 7;             // batch half (0..1)
    const int rbase = bh * 32;
    const f4v* tb = (const f4v*)(tab + (size_t)(f0 + fl) * ROWS * 64 + eq * 8);
    float*     op = out + (size_t)(b0 + rbase) * (F_N * E_N)
                        + (size_t)(f0 + fl) * E_N + eq * 4;

    #pragma unroll
    for (int c = 0; c < 4; ++c) {
        // ---- load cluster: 16 independent gathers, no stores between ----
        float xv[8];
        f4v   a[8], cc[8];
        #pragma unroll
        for (int j = 0; j < 8; ++j) {
            int r  = c * 8 + j;
            int lo = los[(rbase + r) * FH + fl];   // broadcast within e-quad
            xv[j]  = xs[(rbase + r) * FH + fl];
            a[j]   = tb[lo * 16];
            cc[j]  = tb[lo * 16 + 1];
        }
        // ---- store cluster: 8 FMA + NT stores ----
        #pragma unroll
        for (int j = 0; j < 8; ++j) {
            f4v o;
            o.x = fmaf(xv[j], a[j].x, cc[j].x);
            o.y = fmaf(xv[j], a[j].y, cc[j].y);
            o.z = fmaf(xv[j], a[j].z, cc[j].z);
            o.w = fmaf(xv[j], a[j].w, cc[j].w);
            __builtin_nontemporal_store(
                o, (f4v*)(op + (size_t)(c * 8 + j) * (F_N * E_N)));
        }
    }
}

// ---------------------------------------------------------------------------
// Fallback (only if d_ws is too small): direct fp32 compute.
// ---------------------------------------------------------------------------
__global__ __launch_bounds__(256) void direct_kernel(
    const float* __restrict__ x, const float* __restrict__ w1,
    const float* __restrict__ b1, const float* __restrict__ w2,
    const float* __restrict__ b2, float* __restrict__ out)
{
    __shared__ float w1s[H_N], b1s[H_N], b2s[E_N];
    __shared__ float w2s[H_N * E_N];
    const int f   = blockIdx.y;
    const int tid = threadIdx.x;
    if (tid < H_N) { w1s[tid] = w1[f * H_N + tid]; b1s[tid] = b1[f * H_N + tid]; }
    for (int i = tid; i < H_N * E_N; i += 256) w2s[i] = w2[(size_t)f * H_N * E_N + i];
    if (tid < E_N) b2s[tid] = b2[f * E_N + tid];
    __syncthreads();

    const int b  = blockIdx.x * 256 + tid;
    float xv = x[(size_t)b * F_N + f];
    float acc[E_N];
    #pragma unroll
    for (int e = 0; e < E_N; ++e) acc[e] = b2s[e];
    for (int h = 0; h < H_N; ++h) {
        float hv = fmaxf(fmaf(xv, w1s[h], b1s[h]), 0.f);
        #pragma unroll
        for (int e = 0; e < E_N; ++e) acc[e] = fmaf(hv, w2s[h * E_N + e], acc[e]);
    }
    float* op = out + (size_t)b * (F_N * E_N) + (size_t)f * E_N;
    #pragma unroll
    for (int e = 0; e < E_N; e += 4)
        *(float4*)(op + e) = make_float4(acc[e], acc[e + 1], acc[e + 2], acc[e + 3]);
}

extern "C" void kernel_launch(void* const* d_in, const int* in_sizes, int n_in,
                              void* d_out, int out_size, void* d_ws, size_t ws_size,
                              hipStream_t stream) {
    const float* x  = (const float*)d_in[0];
    const float* w1 = (const float*)d_in[1];
    const float* b1 = (const float*)d_in[2];
    const float* w2 = (const float*)d_in[3];
    const float* b2 = (const float*)d_in[4];
    float* out = (float*)d_out;

    const size_t n_ts  = (size_t)F_N * H_N;
    const size_t n_tab = (size_t)F_N * ROWS * 64;
    const size_t need  = (n_ts + n_tab) * sizeof(float);

    if (ws_size >= need) {
        float* ts  = (float*)d_ws;
        float* tab = ts + n_ts;
        build_tables<<<dim3(F_N), dim3(128), 0, stream>>>(w1, b1, w2, b2, ts, tab);
        apply_tables<<<dim3((B_N / NB) * (F_N / FH)), dim3(256), 0, stream>>>(x, ts, tab, out);
    } else {
        direct_kernel<<<dim3(B_N / 256, F_N), dim3(256), 0, stream>>>(x, w1, b1, w2, b2, out);
    }
}

// Round 6
// 291.280 us; speedup vs baseline: 1.0284x; 1.0086x over previous
//
#include <hip/hip_runtime.h>
#include <math.h>

#define B_N 16384
#define F_N 128
#define H_N 128
#define E_N 32
#define ROWS (H_N + 1)   // 129 prefix rows per feature
// Interleaved table row (64 floats = 256 B):
//   row[eq*8 + 0..3] = A[e = eq*4 .. eq*4+3]
//   row[eq*8 + 4..7] = C[e = eq*4 .. eq*4+3]
// -> each apply thread reads its 32 bytes contiguously.

typedef float f4v __attribute__((ext_vector_type(4)));

__device__ __forceinline__ int eidxA(int e) { return ((e >> 2) << 3) | (e & 3); }

// ---------------------------------------------------------------------------
// Kernel A: per-feature table build. relu(x*w1+b1) is linear in x with one
// breakpoint t = -b1/w1. Sort thresholds; prefix tables over the active set.
// (group-parallel scan; table rows e-quad interleaved). ~10 us.
// ---------------------------------------------------------------------------
__global__ __launch_bounds__(128) void build_tables(
    const float* __restrict__ w1, const float* __restrict__ b1,
    const float* __restrict__ w2, const float* __restrict__ b2,
    float* __restrict__ ts_out, float* __restrict__ tab)
{
    __shared__ float w1s[H_N], b1s[H_N], ts[H_N];
    __shared__ int   hidx[H_N];
    __shared__ float w2s[H_N * E_N];   // 16 KB
    __shared__ float dA[H_N * E_N];    // 16 KB
    __shared__ float dC[H_N * E_N];    // 16 KB
    __shared__ float baseA[4 * E_N], baseC[4 * E_N];
    __shared__ float gtA[4 * E_N], gtC[4 * E_N];

    const int f   = blockIdx.x;
    const int tid = threadIdx.x;

    float w1v = w1[f * H_N + tid];
    float b1v = b1[f * H_N + tid];
    w1s[tid] = w1v;
    b1s[tid] = b1v;
    ts[tid]   = (w1v != 0.0f) ? (-b1v / w1v) : INFINITY;
    hidx[tid] = tid;

    // stage w2[f]: 4096 floats = 1024 float4, 8 per thread, coalesced
    {
        const float4* src = (const float4*)(w2 + (size_t)f * H_N * E_N);
        float4*       dst = (float4*)w2s;
        #pragma unroll
        for (int it = 0; it < 8; ++it) dst[it * 128 + tid] = src[it * 128 + tid];
    }
    __syncthreads();

    // bitonic sort ascending by ts, payload hidx
    for (int k = 2; k <= H_N; k <<= 1) {
        for (int j = k >> 1; j > 0; j >>= 1) {
            int ixj = tid ^ j;
            if (ixj > tid) {
                float a = ts[tid], bv = ts[ixj];
                bool up = ((tid & k) == 0);
                bool sw = up ? (a > bv) : (a < bv);
                if (sw) {
                    int ia = hidx[tid];
                    ts[tid] = bv; ts[ixj] = a;
                    hidx[tid] = hidx[ixj]; hidx[ixj] = ia;
                }
            }
            __syncthreads();
        }
    }

    ts_out[f * H_N + tid] = ts[tid];

    const int e = tid & 31;    // embedding lane
    const int g = tid >> 5;    // 0..3 group

    // crossing deltas: group g handles sorted positions g*32..+31
    #pragma unroll 4
    for (int jj = 0; jj < 32; ++jj) {
        int   j   = g * 32 + jj;
        int   p   = hidx[j];
        float w1h = w1s[p], b1h = b1s[p];
        float w2v = w2s[p * E_N + e];
        float s   = (w1h > 0.f) ? 1.f : ((w1h < 0.f) ? -1.f : 0.f);
        dA[j * E_N + e] = s * w1h * w2v;
        dC[j * E_N + e] = s * b1h * w2v;
    }
    // base state at x=-inf: group-partial sums
    {
        float pA = 0.f, pC = 0.f;
        #pragma unroll 4
        for (int hh = 0; hh < 32; ++hh) {
            int   h   = g * 32 + hh;
            float w1h = w1s[h], b1h = b1s[h];
            float w2v = w2s[h * E_N + e];
            if (w1h < 0.f) {
                pA = fmaf(w1h, w2v, pA);
                pC = fmaf(b1h, w2v, pC);
            } else if (w1h == 0.f && b1h > 0.f) {
                pC = fmaf(b1h, w2v, pC);
            }
        }
        baseA[g * E_N + e] = pA;
        baseC[g * E_N + e] = pC;
    }

    // group-local inclusive scan, in place
    {
        float aA = 0.f, aC = 0.f;
        for (int jj = 0; jj < 32; ++jj) {
            int idx = (g * 32 + jj) * E_N + e;
            aA += dA[idx]; dA[idx] = aA;
            aC += dC[idx]; dC[idx] = aC;
        }
        gtA[g * E_N + e] = aA;
        gtC[g * E_N + e] = aC;
    }
    __syncthreads();

    // offset for group g = full base + totals of groups < g
    float offA = baseA[e] + baseA[E_N + e] + baseA[2 * E_N + e] + baseA[3 * E_N + e];
    float offC = baseC[e] + baseC[E_N + e] + baseC[2 * E_N + e] + baseC[3 * E_N + e]
               + b2[f * E_N + e];
    for (int gg = 0; gg < g; ++gg) {
        offA += gtA[gg * E_N + e];
        offC += gtC[gg * E_N + e];
    }

    const size_t base = (size_t)f * ROWS * 64;
    const int    eA   = eidxA(e);
    if (g == 0) {                       // row 0 = base state
        tab[base + eA]     = offA;
        tab[base + eA + 4] = offC;
    }
    // rows g*32+1 .. g*32+32, written by all 128 threads
    #pragma unroll 4
    for (int jj = 0; jj < 32; ++jj) {
        int j = g * 32 + jj;
        tab[base + (size_t)(j + 1) * 64 + eA]     = offA + dA[j * E_N + e];
        tab[base + (size_t)(j + 1) * 64 + eA + 4] = offC + dC[j * E_N + e];
    }
}

// ---------------------------------------------------------------------------
// Kernel B: out[b,f,e] = x*A[f,r,e] + C[f,r,e], r = lower_bound(ts_f, x).
// v8: FULL-ROW blocks for DRAM write locality. A block owns ALL 128
//     features x 16 batch rows -> writes 256 KB fully contiguous; each
//     wave writes 4 rows = 64 KB strictly sequential (ascending 1 KB
//     store instructions), matching the harness fill kernel's 6.4 TB/s
//     access pattern. Previous layout scattered each 16 KB output row
//     across 8 blocks on 8 XCDs -> DRAM-activate-bound at ~2.4 TB/s;
//     that, not occupancy/L2/waitcnt (R3-R5 nulls), is the theory.
//     LDS: thresholds 66 KB + xs 8 KB + los 4 KB = 78.3 KB -> 2 blk/CU.
// ---------------------------------------------------------------------------
#define NB 16   // batch rows per block (all 128 features)

__global__ __launch_bounds__(256, 2) void apply_tables(
    const float* __restrict__ x, const float* __restrict__ ts,
    const float* __restrict__ tab, float* __restrict__ out)
{
    __shared__ float          lds_t[F_N * ROWS];  // 66 KB (stride 129)
    __shared__ float          xs[NB * F_N];       // 8 KB
    __shared__ unsigned short los[NB * F_N];      // 4 KB

    const int tid = threadIdx.x;
    const int b0  = blockIdx.x * NB;

    // stage sorted thresholds: 128*128 = 16384 floats = 4096 float4, 16/thread
    {
        const float4* src = (const float4*)ts;
        #pragma unroll
        for (int it = 0; it < 16; ++it) {
            int    vi  = it * 256 + tid;
            float4 v   = src[vi];
            int    idx = vi * 4;
            int    fl_ = idx >> 7;       // /128
            int    j   = idx & 127;
            float* dst = &lds_t[fl_ * ROWS + j];
            dst[0] = v.x; dst[1] = v.y; dst[2] = v.z; dst[3] = v.w;
        }
    }
    // stage x tile: NB x 128 = 2048 floats = 512 float4, 2/thread
    {
        #pragma unroll
        for (int it = 0; it < 2; ++it) {
            int vi = it * 256 + tid;
            int bl = vi >> 5;            // 32 float4 per row of 128
            int fq = (vi & 31) * 4;
            float4 v = *(const float4*)(x + (size_t)(b0 + bl) * F_N + fq);
            *(float4*)(&xs[bl * F_N + fq]) = v;
        }
    }
    __syncthreads();

    // Phase A: binary search once per (row, feature): 2048 searches/block,
    // 8 per thread, step-major for 8-wide LDS ILP.
    {
        const int fa = tid & 127;        // feature lane
        const int rg = tid >> 7;         // 0..1, rows rg*8..rg*8+7
        const float* tloc = &lds_t[fa * ROWS];
        float xv[8];
        int   lo[8], hi[8];
        #pragma unroll
        for (int j = 0; j < 8; ++j) {
            xv[j] = xs[(rg * 8 + j) * F_N + fa];
            lo[j] = 0; hi[j] = H_N;
        }
        #pragma unroll
        for (int s = 0; s < 7; ++s) {
            #pragma unroll
            for (int j = 0; j < 8; ++j) {
                int  mid = (lo[j] + hi[j]) >> 1;
                bool lt  = tloc[mid] < xv[j];
                lo[j] = lt ? mid + 1 : lo[j];
                hi[j] = lt ? hi[j] : mid;
            }
        }
        #pragma unroll
        for (int j = 0; j < 8; ++j)
            los[(rg * 8 + j) * F_N + fa] = (unsigned short)lo[j];
    }
    __syncthreads();

    // Phase B: per wave, 4 full output rows written strictly sequentially.
    // Lane l handles feature fl = k*8 + (l>>3), e-quad eq = l&7 at step k;
    // store instruction k covers bytes [k*1024, k*1024+1023] of the row.
    const int lane = tid & 63;
    const int wv   = tid >> 6;           // 0..3
    const int eq   = lane & 7;
    const int fo   = lane >> 3;          // feature octet offset 0..7
    const f4v* tbase = (const f4v*)tab + eq * 2;

    #pragma unroll
    for (int rr = 0; rr < 4; ++rr) {
        const int r = wv * 4 + rr;
        const float*          xrow = &xs[r * F_N];
        const unsigned short* lrow = &los[r * F_N];
        float* oprow = out + (size_t)(b0 + r) * (F_N * E_N);

        #pragma unroll
        for (int kc = 0; kc < 4; ++kc) {
            // ---- load cluster: 8 independent gathers ----
            float xv[4];
            f4v   a[4], cc[4];
            #pragma unroll
            for (int jk = 0; jk < 4; ++jk) {
                int k  = kc * 4 + jk;
                int fl = k * 8 + fo;
                int lo = lrow[fl];               // broadcast within e-quad
                xv[jk] = xrow[fl];
                const f4v* tp = tbase + (size_t)(fl * ROWS + lo) * 16;
                a[jk]  = tp[0];
                cc[jk] = tp[1];
            }
            // ---- store cluster: 4 FMA + NT stores, ascending addresses ----
            #pragma unroll
            for (int jk = 0; jk < 4; ++jk) {
                int k = kc * 4 + jk;
                f4v o;
                o.x = fmaf(xv[jk], a[jk].x, cc[jk].x);
                o.y = fmaf(xv[jk], a[jk].y, cc[jk].y);
                o.z = fmaf(xv[jk], a[jk].z, cc[jk].z);
                o.w = fmaf(xv[jk], a[jk].w, cc[jk].w);
                __builtin_nontemporal_store(
                    o, (f4v*)(oprow + k * 256 + fo * 32 + eq * 4));
            }
        }
    }
}

// ---------------------------------------------------------------------------
// Fallback (only if d_ws is too small): direct fp32 compute.
// ---------------------------------------------------------------------------
__global__ __launch_bounds__(256) void direct_kernel(
    const float* __restrict__ x, const float* __restrict__ w1,
    const float* __restrict__ b1, const float* __restrict__ w2,
    const float* __restrict__ b2, float* __restrict__ out)
{
    __shared__ float w1s[H_N], b1s[H_N], b2s[E_N];
    __shared__ float w2s[H_N * E_N];
    const int f   = blockIdx.y;
    const int tid = threadIdx.x;
    if (tid < H_N) { w1s[tid] = w1[f * H_N + tid]; b1s[tid] = b1[f * H_N + tid]; }
    for (int i = tid; i < H_N * E_N; i += 256) w2s[i] = w2[(size_t)f * H_N * E_N + i];
    if (tid < E_N) b2s[tid] = b2[f * E_N + tid];
    __syncthreads();

    const int b  = blockIdx.x * 256 + tid;
    float xv = x[(size_t)b * F_N + f];
    float acc[E_N];
    #pragma unroll
    for (int e = 0; e < E_N; ++e) acc[e] = b2s[e];
    for (int h = 0; h < H_N; ++h) {
        float hv = fmaxf(fmaf(xv, w1s[h], b1s[h]), 0.f);
        #pragma unroll
        for (int e = 0; e < E_N; ++e) acc[e] = fmaf(hv, w2s[h * E_N + e], acc[e]);
    }
    float* op = out + (size_t)b * (F_N * E_N) + (size_t)f * E_N;
    #pragma unroll
    for (int e = 0; e < E_N; e += 4)
        *(float4*)(op + e) = make_float4(acc[e], acc[e + 1], acc[e + 2], acc[e + 3]);
}

extern "C" void kernel_launch(void* const* d_in, const int* in_sizes, int n_in,
                              void* d_out, int out_size, void* d_ws, size_t ws_size,
                              hipStream_t stream) {
    const float* x  = (const float*)d_in[0];
    const float* w1 = (const float*)d_in[1];
    const float* b1 = (const float*)d_in[2];
    const float* w2 = (const float*)d_in[3];
    const float* b2 = (const float*)d_in[4];
    float* out = (float*)d_out;

    const size_t n_ts  = (size_t)F_N * H_N;
    const size_t n_tab = (size_t)F_N * ROWS * 64;
    const size_t need  = (n_ts + n_tab) * sizeof(float);

    if (ws_size >= need) {
        float* ts  = (float*)d_ws;
        float* tab = ts + n_ts;
        build_tables<<<dim3(F_N), dim3(128), 0, stream>>>(w1, b1, w2, b2, ts, tab);
        apply_tables<<<dim3(B_N / NB), dim3(256), 0, stream>>>(x, ts, tab, out);
    } else {
        direct_kernel<<<dim3(B_N / 256, F_N), dim3(256), 0, stream>>>(x, w1, b1, w2, b2, out);
    }
}